// Round 8
// baseline (404.377 us; speedup 1.0000x reference)
//
#include <hip/hip_runtime.h>
#include <hip/hip_cooperative_groups.h>

namespace cg = cooperative_groups;

constexpr int NN = 100000;
constexpr int NE = 3200000;
constexpr int DD = 128;
constexpr int NB = 782;          // ceil(NN/128) buckets of 128 nodes
constexpr int RND = 8192;        // edges binned per block (391 blocks)
#define BN_EPS 1e-5f

typedef __attribute__((ext_vector_type(8))) short bf16x8;
typedef __attribute__((ext_vector_type(4))) float f32x4;
typedef __attribute__((ext_vector_type(2))) float f32x2;

// ---- workspace layout (bytes) ----
constexpr size_t WS_CNT   = 0;            // int[NB]
constexpr size_t WS_COFF  = 4096;         // int[NB+1]
constexpr size_t WS_CUR   = 8192;         // int[NB]
constexpr size_t WS_FLAG  = 12288;        // int[1]
constexpr size_t WS_BNSUM = 12800;        // float[128]
constexpr size_t WS_BNSQ  = 13312;        // float[128]
constexpr size_t WS_ZERO  = 16384;        // memset range
constexpr size_t WS_DEG   = 16384;        // int[NN]
constexpr size_t WS_OFF   = 416384;       // int[NN]
constexpr size_t WS_CSR   = 816384;       // int[NE]
constexpr size_t WS_WT    = 13616384;     // ushort[128*256] transposed bf16 W (64KB)
// d_out first half (out_raw, 51.2MB): xq (fp8[NN*128], 12.8MB) lives at offset 0,
//   dead after k_agg; k_gemm overwrites with x_raw.
// d_out second half (out_bn, 51.2MB): bin (uint[NE]) at [0,12.8M) until k_csr;
//   aggb (bf16[NN*128]) at [0,25.6M) from k_agg; xb (bf16[NN*128]) at [25.6M,51.2M).
//   All dead before k_gemm phase 2 writes x_deskewed over them (grid-synced).

__device__ inline unsigned bf16rne(float f) {
    unsigned u = __float_as_uint(f);
    return (u + 0x7fffu + ((u >> 16) & 1u)) >> 16;
}

#if __has_builtin(__builtin_amdgcn_cvt_pk_f32_fp8)
__device__ inline f32x2 fp8x2_to_f32(unsigned u) {
    return __builtin_amdgcn_cvt_pk_f32_fp8((int)u, false);
}
__device__ inline unsigned f32x4_to_fp8(float4 v) {
    int w = __builtin_amdgcn_cvt_pk_fp8_f32(v.x, v.y, 0, false);
    w = __builtin_amdgcn_cvt_pk_fp8_f32(v.z, v.w, w, true);
    return (unsigned)w;
}
#else
__device__ inline float fp8_to_f32_1(unsigned b) {
    unsigned s = (b & 0x80u) << 24;
    unsigned em = b & 0x7fu;
    float f;
    if (em >= 8) f = __uint_as_float((em << 20) + (120u << 23));
    else f = (float)em * 0.001953125f;
    return __uint_as_float(__float_as_uint(f) | s);
}
__device__ inline f32x2 fp8x2_to_f32(unsigned u) {
    f32x2 r;
    r[0] = fp8_to_f32_1(u & 0xffu);
    r[1] = fp8_to_f32_1((u >> 8) & 0xffu);
    return r;
}
__device__ inline unsigned f32_to_fp8_1(float f) {
    unsigned s = (__float_as_uint(f) >> 24) & 0x80u;
    float a = fabsf(f);
    if (!(a > 0.f)) return s;
    if (a >= 448.f) return s | 0x7Eu;
    int e = (int)(__float_as_uint(a) >> 23) - 127;
    if (e < -6) e = -6;
    float step = __uint_as_float((unsigned)(e - 3 + 127) << 23);
    int m = (int)rintf(a / step);
    if (m >= 16) { e += 1; m = 8; }
    if (m >= 8) return s | (unsigned)((e + 7) << 3) | (unsigned)(m - 8);
    return s | (unsigned)m;
}
__device__ inline unsigned f32x4_to_fp8(float4 v) {
    return f32_to_fp8_1(v.x) | (f32_to_fp8_1(v.y) << 8) |
           (f32_to_fp8_1(v.z) << 16) | (f32_to_fp8_1(v.w) << 24);
}
#endif

// Detect whether edge_index arrived as int64 (odd int32 words all zero).
__global__ void k_detect(const int* __restrict__ ei, int* __restrict__ flag) {
    int lane = threadIdx.x;
    int v = ei[2 * lane + 1];
    unsigned long long b = __ballot(v == 0);
    if (lane == 0) *flag = (b == ~0ull) ? 1 : 0;
}

// Build bf16 copy (for GEMM) and fp8 copy (for gather) of x in one pass.
__global__ __launch_bounds__(256) void k_prep(const float* __restrict__ x,
                                              unsigned* __restrict__ xb,
                                              unsigned* __restrict__ xq) {
    int total = NN * DD / 4;
    for (int i = blockIdx.x * 256 + threadIdx.x; i < total; i += gridDim.x * 256) {
        float4 v = ((const float4*)x)[i];
        unsigned a = (bf16rne(v.y) << 16) | bf16rne(v.x);
        unsigned b = (bf16rne(v.w) << 16) | bf16rne(v.z);
        ((uint2*)xb)[i] = make_uint2(a, b);
        xq[i] = f32x4_to_fp8(v);
    }
}

// Transposed bf16 weights: Wt[n][k] (k<128 -> Wl[k][n], else Wr[k-128][n]).
__global__ __launch_bounds__(256) void k_prepw(const float* __restrict__ Wl,
                                               const float* __restrict__ Wr,
                                               unsigned short* __restrict__ Wt) {
    int idx = blockIdx.x * 256 + threadIdx.x;   // 32768 total
    int n = idx >> 8, k = idx & 255;
    float v = (k < 128) ? Wl[(size_t)k * DD + n] : Wr[(size_t)(k - 128) * DD + n];
    Wt[idx] = (unsigned short)bf16rne(v);
}

// Coarse bucket histogram (782 buckets) via block-LDS hist + one flush.
__global__ __launch_bounds__(256) void k_bcount(const int* __restrict__ ei,
                                                const int* __restrict__ flag,
                                                int* __restrict__ cnt) {
    __shared__ int hist[NB];
    for (int i = threadIdx.x; i < NB; i += 256) hist[i] = 0;
    __syncthreads();
    int i64 = *flag;
    int stride = gridDim.x * 256;
    for (int e = blockIdx.x * 256 + threadIdx.x; e < NE; e += stride) {
        int dst = i64 ? ei[2 * (NE + e)] : ei[NE + e];
        atomicAdd(&hist[dst >> 7], 1);
    }
    __syncthreads();
    for (int i = threadIdx.x; i < NB; i += 256) {
        int c = hist[i];
        if (c) atomicAdd(&cnt[i], c);
    }
}

// Exclusive scan of the 782 bucket counts.
__global__ __launch_bounds__(256) void k_scan(const int* __restrict__ cnt,
                                              int* __restrict__ coff,
                                              int* __restrict__ cur) {
    __shared__ int s[NB];
    for (int i = threadIdx.x; i < NB; i += 256) s[i] = cnt[i];
    __syncthreads();
    if (threadIdx.x == 0) {
        int acc = 0;
        for (int i = 0; i < NB; ++i) { int c = s[i]; s[i] = acc; acc += c; }
    }
    __syncthreads();
    for (int i = threadIdx.x; i < NB; i += 256) { coff[i] = s[i]; cur[i] = s[i]; }
    if (threadIdx.x == 0) coff[NB] = NE;
}

// Bin edges by coarse bucket with per-block batched cursor reservation.
__global__ __launch_bounds__(256) void k_bin(const int* __restrict__ ei,
                                             const int* __restrict__ flag,
                                             int* __restrict__ cur,
                                             unsigned* __restrict__ bin) {
    __shared__ int hist[NB];
    __shared__ int base[NB];
    __shared__ int rk[NB];
    int tid = threadIdx.x;
    for (int i = tid; i < NB; i += 256) { hist[i] = 0; rk[i] = 0; }
    __syncthreads();
    int i64 = *flag;
    int e0 = blockIdx.x * RND;
    for (int j = tid; j < RND; j += 256) {
        int e = e0 + j;
        if (e < NE) {
            int dst = i64 ? ei[2 * (NE + e)] : ei[NE + e];
            atomicAdd(&hist[dst >> 7], 1);
        }
    }
    __syncthreads();
    for (int b = tid; b < NB; b += 256) {
        int c = hist[b];
        if (c > 0) base[b] = atomicAdd(&cur[b], c);
    }
    __syncthreads();
    for (int j = tid; j < RND; j += 256) {
        int e = e0 + j;
        if (e < NE) {
            int src = i64 ? ei[2 * e] : ei[e];
            int dst = i64 ? ei[2 * (NE + e)] : ei[NE + e];
            int b = dst >> 7;
            int r = atomicAdd(&rk[b], 1);
            bin[base[b] + r] = ((unsigned)src << 7) | (unsigned)(dst & 127);
        }
    }
}

// Per-bucket counting sort -> node-grouped CSR + deg/off.
__global__ __launch_bounds__(256) void k_csr(const unsigned* __restrict__ bin,
                                             const int* __restrict__ coff,
                                             int* __restrict__ csr,
                                             int* __restrict__ deg,
                                             int* __restrict__ off) {
    __shared__ int hist[128];
    __shared__ int sb[128];
    __shared__ int curs[128];
    int b = blockIdx.x;
    int tid = threadIdx.x;
    if (tid < 128) hist[tid] = 0;
    __syncthreads();
    int e0 = coff[b], e1 = coff[b + 1];
    for (int j = e0 + tid; j < e1; j += 256)
        atomicAdd(&hist[bin[j] & 127], 1);
    __syncthreads();
    if (tid == 0) {
        int acc = 0;
        for (int i = 0; i < 128; ++i) { sb[i] = acc; acc += hist[i]; }
    }
    __syncthreads();
    if (tid < 128) curs[tid] = sb[tid];
    __syncthreads();
    for (int j = e0 + tid; j < e1; j += 256) {
        unsigned p = bin[j];
        int d = p & 127;
        int r = atomicAdd(&curs[d], 1);
        csr[e0 + r] = (int)(p >> 7);
    }
    int n = b * 128 + tid;
    if (tid < 128 && n < NN) {
        deg[n] = hist[tid];
        off[n] = e0 + sb[tid];
    }
}

// Wave-per-node gather-sum from the fp8 copy: one ushort (2 fp8) per lane =
// full 128B row (one cache line) per wave-instruction. fp32 accumulate.
__global__ __launch_bounds__(256) void k_agg(const unsigned short* __restrict__ xq,
                                             const int* __restrict__ csr,
                                             const int* __restrict__ deg,
                                             const int* __restrict__ off,
                                             unsigned* __restrict__ aggb) {
    int w = (blockIdx.x * 256 + threadIdx.x) >> 6;
    int lane = threadIdx.x & 63;
    if (w >= NN) return;
    int dg = deg[w];
    int o = off[w];
    float ax = 0.f, ay = 0.f;
    int j = 0;
    for (; j + 4 <= dg; j += 4) {
        int s0 = csr[o + j];
        int s1 = csr[o + j + 1];
        int s2 = csr[o + j + 2];
        int s3 = csr[o + j + 3];
        unsigned u0 = xq[(size_t)s0 * 64 + lane];
        unsigned u1 = xq[(size_t)s1 * 64 + lane];
        unsigned u2 = xq[(size_t)s2 * 64 + lane];
        unsigned u3 = xq[(size_t)s3 * 64 + lane];
        f32x2 f0 = fp8x2_to_f32(u0);
        f32x2 f1 = fp8x2_to_f32(u1);
        f32x2 f2 = fp8x2_to_f32(u2);
        f32x2 f3 = fp8x2_to_f32(u3);
        ax += (f0[0] + f1[0]) + (f2[0] + f3[0]);
        ay += (f0[1] + f1[1]) + (f2[1] + f3[1]);
    }
    for (; j < dg; ++j) {
        int s = csr[o + j];
        f32x2 f = fp8x2_to_f32(xq[(size_t)s * 64 + lane]);
        ax += f[0];
        ay += f[1];
    }
    float inv = 1.0f / fmaxf((float)dg, 1.0f);
    unsigned lo = bf16rne(ax * inv);   // feature 2*lane
    unsigned hi = bf16rne(ay * inv);   // feature 2*lane+1
    aggb[(size_t)w * 64 + lane] = (hi << 16) | lo;
}

// MFMA GEMM: x_raw = [agg | x]_bf16 @ Wt^T + b, BN stats fused into epilogue.
// COOP variant: grid-sync then normalize from live accumulators (k_norm fused).
template<bool COOP>
__global__ __launch_bounds__(256, 4) void k_gemm(const unsigned short* __restrict__ aggb,
                                                 const unsigned short* __restrict__ xb,
                                                 const unsigned short* __restrict__ Wt,
                                                 const float* __restrict__ bl,
                                                 const float* __restrict__ gamma,
                                                 const float* __restrict__ beta,
                                                 float* __restrict__ out_raw,
                                                 float* __restrict__ out_bn,
                                                 float* __restrict__ bn_sum,
                                                 float* __restrict__ bn_sq) {
    __shared__ float s_s[4][128];
    __shared__ float s_q[4][128];
    int tid = threadIdx.x;
    int wv = tid >> 6, lane = tid & 63;
    int l15 = lane & 15, lhi = lane >> 4;
    int mr = blockIdx.x * 128 + wv * 32;

    int r0 = mr + l15;       if (r0 > NN - 1) r0 = NN - 1;
    int r1 = mr + 16 + l15;  if (r1 > NN - 1) r1 = NN - 1;
    const unsigned short* a0p = aggb + (size_t)r0 * DD;
    const unsigned short* a1p = aggb + (size_t)r1 * DD;
    const unsigned short* x0p = xb + (size_t)r0 * DD;
    const unsigned short* x1p = xb + (size_t)r1 * DD;

    f32x4 acc[2][8];
    #pragma unroll
    for (int m = 0; m < 2; ++m)
        #pragma unroll
        for (int nt = 0; nt < 8; ++nt)
            acc[m][nt] = (f32x4){0.f, 0.f, 0.f, 0.f};

    #pragma unroll
    for (int ks = 0; ks < 8; ++ks) {
        int kk = (ks & 3) * 32 + lhi * 8;
        bf16x8 a0, a1;
        if (ks < 4) {
            a0 = *(const bf16x8*)(a0p + kk);
            a1 = *(const bf16x8*)(a1p + kk);
        } else {
            a0 = *(const bf16x8*)(x0p + kk);
            a1 = *(const bf16x8*)(x1p + kk);
        }
        #pragma unroll
        for (int nt = 0; nt < 8; ++nt) {
            bf16x8 b = *(const bf16x8*)(Wt + (size_t)(nt * 16 + l15) * 256 + ks * 32 + lhi * 8);
            acc[0][nt] = __builtin_amdgcn_mfma_f32_16x16x32_bf16(a0, b, acc[0][nt], 0, 0, 0);
            acc[1][nt] = __builtin_amdgcn_mfma_f32_16x16x32_bf16(a1, b, acc[1][nt], 0, 0, 0);
        }
    }

    // phase 1: bias + store x_raw (D layout: row=lhi*4+reg, col=l15) + stats
    float bias8[8];
    #pragma unroll
    for (int nt = 0; nt < 8; ++nt) bias8[nt] = bl[nt * 16 + l15];

    float s8[8] = {}, q8[8] = {};
    #pragma unroll
    for (int m = 0; m < 2; ++m) {
        #pragma unroll
        for (int r = 0; r < 4; ++r) {
            int row = mr + m * 16 + lhi * 4 + r;
            if (row < NN) {
                #pragma unroll
                for (int nt = 0; nt < 8; ++nt) {
                    float v = acc[m][nt][r] + bias8[nt];
                    out_raw[(size_t)row * DD + nt * 16 + l15] = v;
                    s8[nt] += v;
                    q8[nt] += v * v;
                }
            }
        }
    }

    #pragma unroll
    for (int nt = 0; nt < 8; ++nt) {
        s8[nt] += __shfl_xor(s8[nt], 16);
        s8[nt] += __shfl_xor(s8[nt], 32);
        q8[nt] += __shfl_xor(q8[nt], 16);
        q8[nt] += __shfl_xor(q8[nt], 32);
    }
    if (lhi == 0) {
        #pragma unroll
        for (int nt = 0; nt < 8; ++nt) {
            s_s[wv][nt * 16 + l15] = s8[nt];
            s_q[wv][nt * 16 + l15] = q8[nt];
        }
    }
    __syncthreads();
    if (tid < 128) {
        float ts = s_s[0][tid] + s_s[1][tid] + s_s[2][tid] + s_s[3][tid];
        float tq = s_q[0][tid] + s_q[1][tid] + s_q[2][tid] + s_q[3][tid];
        atomicAdd(&bn_sum[tid], ts);
        atomicAdd(&bn_sq[tid], tq);
    }

    if constexpr (COOP) {
        cg::this_grid().sync();
        // phase 2: normalize from live accumulators, write x_deskewed
        const float invN = 1.0f / (float)NN;
        #pragma unroll
        for (int nt = 0; nt < 8; ++nt) {
            int c = nt * 16 + l15;
            float sm = bn_sum[c];
            float sq = bn_sq[c];
            float mu = sm * invN;
            float var = sq * invN - mu * mu;
            float scale = gamma[c] * rsqrtf(var + BN_EPS);
            float shift = (bias8[nt] - mu) * scale + beta[c];
            #pragma unroll
            for (int m = 0; m < 2; ++m) {
                #pragma unroll
                for (int r = 0; r < 4; ++r) {
                    int row = mr + m * 16 + lhi * 4 + r;
                    if (row < NN)
                        out_bn[(size_t)row * DD + c] = acc[m][nt][r] * scale + shift;
                }
            }
        }
    }
}

// Fallback normalize pass (only if cooperative launch is rejected).
__global__ __launch_bounds__(256) void k_norm(const float* __restrict__ raw,
                                              const float* __restrict__ bn_sum,
                                              const float* __restrict__ bn_sq,
                                              const float* __restrict__ gamma,
                                              const float* __restrict__ beta,
                                              float* __restrict__ out) {
    const float invN = 1.0f / (float)NN;
    int total = NN * DD / 4;
    for (int idx = blockIdx.x * 256 + threadIdx.x; idx < total; idx += gridDim.x * 256) {
        int cp = idx & 31;
        float4 v = ((const float4*)raw)[idx];
        float4 s = ((const float4*)bn_sum)[cp];
        float4 q = ((const float4*)bn_sq)[cp];
        float4 g = ((const float4*)gamma)[cp];
        float4 b = ((const float4*)beta)[cp];
        float4 o;
        { float mu = s.x * invN; float var = q.x * invN - mu * mu;
          o.x = (v.x - mu) * rsqrtf(var + BN_EPS) * g.x + b.x; }
        { float mu = s.y * invN; float var = q.y * invN - mu * mu;
          o.y = (v.y - mu) * rsqrtf(var + BN_EPS) * g.y + b.y; }
        { float mu = s.z * invN; float var = q.z * invN - mu * mu;
          o.z = (v.z - mu) * rsqrtf(var + BN_EPS) * g.z + b.z; }
        { float mu = s.w * invN; float var = q.w * invN - mu * mu;
          o.w = (v.w - mu) * rsqrtf(var + BN_EPS) * g.w + b.w; }
        ((float4*)out)[idx] = o;
    }
}

extern "C" void kernel_launch(void* const* d_in, const int* in_sizes, int n_in,
                              void* d_out, int out_size, void* d_ws, size_t ws_size,
                              hipStream_t stream) {
    const float* x     = (const float*)d_in[0];
    const int*   ei    = (const int*)d_in[1];
    const float* Wl    = (const float*)d_in[2];
    const float* bl    = (const float*)d_in[3];
    const float* Wr    = (const float*)d_in[4];
    const float* gamma = (const float*)d_in[5];
    const float* beta  = (const float*)d_in[6];

    float* out_raw = (float*)d_out;                       // [NN][DD] x_raw
    float* out_bn  = out_raw + (size_t)NN * DD;           // [NN][DD] x_deskewed
    unsigned* xq   = (unsigned*)d_out;                    // fp8[NN*128] in out_raw half
    unsigned* bin  = (unsigned*)out_bn;                   // uint[NE]
    unsigned* aggb = (unsigned*)out_bn;                   // bf16[NN*128] packed
    unsigned* xb   = (unsigned*)((char*)out_bn + (size_t)NN * DD * 2); // bf16[NN*128]

    char* ws = (char*)d_ws;
    int*   cnt    = (int*)(ws + WS_CNT);
    int*   coff   = (int*)(ws + WS_COFF);
    int*   cur    = (int*)(ws + WS_CUR);
    int*   flag   = (int*)(ws + WS_FLAG);
    float* bn_sum = (float*)(ws + WS_BNSUM);
    float* bn_sq  = (float*)(ws + WS_BNSQ);
    int*   deg    = (int*)(ws + WS_DEG);
    int*   off    = (int*)(ws + WS_OFF);
    int*   csr    = (int*)(ws + WS_CSR);
    unsigned short* Wt = (unsigned short*)(ws + WS_WT);

    hipMemsetAsync(d_ws, 0, WS_ZERO, stream);

    k_detect<<<1, 64, 0, stream>>>(ei, flag);
    k_prep<<<2048, 256, 0, stream>>>(x, xb, xq);
    k_prepw<<<128, 256, 0, stream>>>(Wl, Wr, Wt);
    k_bcount<<<512, 256, 0, stream>>>(ei, flag, cnt);
    k_scan<<<1, 256, 0, stream>>>(cnt, coff, cur);
    k_bin<<<(NE + RND - 1) / RND, 256, 0, stream>>>(ei, flag, cur, bin);
    k_csr<<<NB, 256, 0, stream>>>(bin, coff, csr, deg, off);
    k_agg<<<(NN * 64 + 255) / 256, 256, 0, stream>>>((const unsigned short*)xq, csr, deg, off, aggb);

    const unsigned short* aggb_h = (const unsigned short*)aggb;
    const unsigned short* xb_h   = (const unsigned short*)xb;
    const unsigned short* Wt_h   = Wt;
    void* kargs[] = {(void*)&aggb_h, (void*)&xb_h, (void*)&Wt_h, (void*)&bl,
                     (void*)&gamma, (void*)&beta, (void*)&out_raw, (void*)&out_bn,
                     (void*)&bn_sum, (void*)&bn_sq};
    hipError_t err = hipLaunchCooperativeKernel((void*)k_gemm<true>, dim3(NB), dim3(256),
                                                kargs, 0, stream);
    if (err != hipSuccess) {
        // fallback: non-cooperative GEMM + separate normalize pass
        k_gemm<false><<<NB, 256, 0, stream>>>(aggb_h, xb_h, Wt_h, bl, gamma, beta,
                                              out_raw, out_bn, bn_sum, bn_sq);
        k_norm<<<4096, 256, 0, stream>>>(out_raw, bn_sum, bn_sq, gamma, beta, out_bn);
    }
}

// Round 9
// 300.056 us; speedup vs baseline: 1.3477x; 1.3477x over previous
//
#include <hip/hip_runtime.h>

constexpr int NN = 100000;
constexpr int NE = 3200000;
constexpr int DD = 128;
constexpr int NB = 782;          // ceil(NN/128) buckets of 128 nodes
constexpr int RND = 8192;        // edges binned per block (391 blocks)
#define BN_EPS 1e-5f

typedef __attribute__((ext_vector_type(8))) short bf16x8;
typedef __attribute__((ext_vector_type(4))) float f32x4;
typedef __attribute__((ext_vector_type(2))) float f32x2;

// ---- workspace layout (bytes) ----
constexpr size_t WS_CNT   = 0;            // int[NB]
constexpr size_t WS_COFF  = 4096;         // int[NB+1]
constexpr size_t WS_CUR   = 8192;         // int[NB]
constexpr size_t WS_FLAG  = 12288;        // int[1]
constexpr size_t WS_BNSUM = 12800;        // float[128]
constexpr size_t WS_BNSQ  = 13312;        // float[128]
constexpr size_t WS_ZERO  = 16384;        // memset range
constexpr size_t WS_DEG   = 16384;        // int[NN]
constexpr size_t WS_OFF   = 416384;       // int[NN]
constexpr size_t WS_CSR   = 816384;       // int[NE]
constexpr size_t WS_WT    = 13616384;     // ushort[128*256] transposed bf16 W (64KB)
// d_out first half (out_raw, 51.2MB): xq (fp8[NN*128], 12.8MB) at offset 0,
//   dead after k_agg; k_gemm overwrites with x_raw.
// d_out second half (out_bn, 51.2MB): bin (uint[NE]) at [0,12.8M) until k_csr;
//   aggb (bf16[NN*128]) at [0,25.6M) from k_agg; xb (bf16[NN*128]) at [25.6M,51.2M).
//   All dead before k_norm writes x_deskewed.

__device__ inline unsigned bf16rne(float f) {
    unsigned u = __float_as_uint(f);
    return (u + 0x7fffu + ((u >> 16) & 1u)) >> 16;
}

#if __has_builtin(__builtin_amdgcn_cvt_pk_f32_fp8)
__device__ inline f32x2 fp8x2_to_f32(unsigned u) {
    return __builtin_amdgcn_cvt_pk_f32_fp8((int)u, false);
}
__device__ inline unsigned f32x4_to_fp8(float4 v) {
    int w = __builtin_amdgcn_cvt_pk_fp8_f32(v.x, v.y, 0, false);
    w = __builtin_amdgcn_cvt_pk_fp8_f32(v.z, v.w, w, true);
    return (unsigned)w;
}
#else
__device__ inline float fp8_to_f32_1(unsigned b) {
    unsigned s = (b & 0x80u) << 24;
    unsigned em = b & 0x7fu;
    float f;
    if (em >= 8) f = __uint_as_float((em << 20) + (120u << 23));
    else f = (float)em * 0.001953125f;
    return __uint_as_float(__float_as_uint(f) | s);
}
__device__ inline f32x2 fp8x2_to_f32(unsigned u) {
    f32x2 r;
    r[0] = fp8_to_f32_1(u & 0xffu);
    r[1] = fp8_to_f32_1((u >> 8) & 0xffu);
    return r;
}
__device__ inline unsigned f32_to_fp8_1(float f) {
    unsigned s = (__float_as_uint(f) >> 24) & 0x80u;
    float a = fabsf(f);
    if (!(a > 0.f)) return s;
    if (a >= 448.f) return s | 0x7Eu;
    int e = (int)(__float_as_uint(a) >> 23) - 127;
    if (e < -6) e = -6;
    float step = __uint_as_float((unsigned)(e - 3 + 127) << 23);
    int m = (int)rintf(a / step);
    if (m >= 16) { e += 1; m = 8; }
    if (m >= 8) return s | (unsigned)((e + 7) << 3) | (unsigned)(m - 8);
    return s | (unsigned)m;
}
__device__ inline unsigned f32x4_to_fp8(float4 v) {
    return f32_to_fp8_1(v.x) | (f32_to_fp8_1(v.y) << 8) |
           (f32_to_fp8_1(v.z) << 16) | (f32_to_fp8_1(v.w) << 24);
}
#endif

// Detect whether edge_index arrived as int64 (odd int32 words all zero).
__global__ void k_detect(const int* __restrict__ ei, int* __restrict__ flag) {
    int lane = threadIdx.x;
    int v = ei[2 * lane + 1];
    unsigned long long b = __ballot(v == 0);
    if (lane == 0) *flag = (b == ~0ull) ? 1 : 0;
}

// Build bf16 copy (for GEMM) and fp8 copy (for gather) of x in one pass.
__global__ __launch_bounds__(256) void k_prep(const float* __restrict__ x,
                                              unsigned* __restrict__ xb,
                                              unsigned* __restrict__ xq) {
    int total = NN * DD / 4;
    for (int i = blockIdx.x * 256 + threadIdx.x; i < total; i += gridDim.x * 256) {
        float4 v = ((const float4*)x)[i];
        unsigned a = (bf16rne(v.y) << 16) | bf16rne(v.x);
        unsigned b = (bf16rne(v.w) << 16) | bf16rne(v.z);
        ((uint2*)xb)[i] = make_uint2(a, b);
        xq[i] = f32x4_to_fp8(v);
    }
}

// Transposed bf16 weights: Wt[n][k] (k<128 -> Wl[k][n], else Wr[k-128][n]).
__global__ __launch_bounds__(256) void k_prepw(const float* __restrict__ Wl,
                                               const float* __restrict__ Wr,
                                               unsigned short* __restrict__ Wt) {
    int idx = blockIdx.x * 256 + threadIdx.x;   // 32768 total
    int n = idx >> 8, k = idx & 255;
    float v = (k < 128) ? Wl[(size_t)k * DD + n] : Wr[(size_t)(k - 128) * DD + n];
    Wt[idx] = (unsigned short)bf16rne(v);
}

// Coarse bucket histogram (782 buckets) via block-LDS hist + one flush.
__global__ __launch_bounds__(256) void k_bcount(const int* __restrict__ ei,
                                                const int* __restrict__ flag,
                                                int* __restrict__ cnt) {
    __shared__ int hist[NB];
    for (int i = threadIdx.x; i < NB; i += 256) hist[i] = 0;
    __syncthreads();
    int i64 = *flag;
    int stride = gridDim.x * 256;
    for (int e = blockIdx.x * 256 + threadIdx.x; e < NE; e += stride) {
        int dst = i64 ? ei[2 * (NE + e)] : ei[NE + e];
        atomicAdd(&hist[dst >> 7], 1);
    }
    __syncthreads();
    for (int i = threadIdx.x; i < NB; i += 256) {
        int c = hist[i];
        if (c) atomicAdd(&cnt[i], c);
    }
}

// Exclusive scan of the 782 bucket counts.
__global__ __launch_bounds__(256) void k_scan(const int* __restrict__ cnt,
                                              int* __restrict__ coff,
                                              int* __restrict__ cur) {
    __shared__ int s[NB];
    for (int i = threadIdx.x; i < NB; i += 256) s[i] = cnt[i];
    __syncthreads();
    if (threadIdx.x == 0) {
        int acc = 0;
        for (int i = 0; i < NB; ++i) { int c = s[i]; s[i] = acc; acc += c; }
    }
    __syncthreads();
    for (int i = threadIdx.x; i < NB; i += 256) { coff[i] = s[i]; cur[i] = s[i]; }
    if (threadIdx.x == 0) coff[NB] = NE;
}

// Bin edges by coarse bucket with per-block batched cursor reservation.
__global__ __launch_bounds__(256) void k_bin(const int* __restrict__ ei,
                                             const int* __restrict__ flag,
                                             int* __restrict__ cur,
                                             unsigned* __restrict__ bin) {
    __shared__ int hist[NB];
    __shared__ int base[NB];
    __shared__ int rk[NB];
    int tid = threadIdx.x;
    for (int i = tid; i < NB; i += 256) { hist[i] = 0; rk[i] = 0; }
    __syncthreads();
    int i64 = *flag;
    int e0 = blockIdx.x * RND;
    for (int j = tid; j < RND; j += 256) {
        int e = e0 + j;
        if (e < NE) {
            int dst = i64 ? ei[2 * (NE + e)] : ei[NE + e];
            atomicAdd(&hist[dst >> 7], 1);
        }
    }
    __syncthreads();
    for (int b = tid; b < NB; b += 256) {
        int c = hist[b];
        if (c > 0) base[b] = atomicAdd(&cur[b], c);
    }
    __syncthreads();
    for (int j = tid; j < RND; j += 256) {
        int e = e0 + j;
        if (e < NE) {
            int src = i64 ? ei[2 * e] : ei[e];
            int dst = i64 ? ei[2 * (NE + e)] : ei[NE + e];
            int b = dst >> 7;
            int r = atomicAdd(&rk[b], 1);
            bin[base[b] + r] = ((unsigned)src << 7) | (unsigned)(dst & 127);
        }
    }
}

// Per-bucket counting sort -> node-grouped CSR + deg/off.
__global__ __launch_bounds__(256) void k_csr(const unsigned* __restrict__ bin,
                                             const int* __restrict__ coff,
                                             int* __restrict__ csr,
                                             int* __restrict__ deg,
                                             int* __restrict__ off) {
    __shared__ int hist[128];
    __shared__ int sb[128];
    __shared__ int curs[128];
    int b = blockIdx.x;
    int tid = threadIdx.x;
    if (tid < 128) hist[tid] = 0;
    __syncthreads();
    int e0 = coff[b], e1 = coff[b + 1];
    for (int j = e0 + tid; j < e1; j += 256)
        atomicAdd(&hist[bin[j] & 127], 1);
    __syncthreads();
    if (tid == 0) {
        int acc = 0;
        for (int i = 0; i < 128; ++i) { sb[i] = acc; acc += hist[i]; }
    }
    __syncthreads();
    if (tid < 128) curs[tid] = sb[tid];
    __syncthreads();
    for (int j = e0 + tid; j < e1; j += 256) {
        unsigned p = bin[j];
        int d = p & 127;
        int r = atomicAdd(&curs[d], 1);
        csr[e0 + r] = (int)(p >> 7);
    }
    int n = b * 128 + tid;
    if (tid < 128 && n < NN) {
        deg[n] = hist[tid];
        off[n] = e0 + sb[tid];
    }
}

// Wave-per-node gather-sum from the fp8 copy: one ushort (2 fp8) per lane =
// full 128B row (one cache line) per wave-instruction. fp32 accumulate.
__global__ __launch_bounds__(256) void k_agg(const unsigned short* __restrict__ xq,
                                             const int* __restrict__ csr,
                                             const int* __restrict__ deg,
                                             const int* __restrict__ off,
                                             unsigned* __restrict__ aggb) {
    int w = (blockIdx.x * 256 + threadIdx.x) >> 6;
    int lane = threadIdx.x & 63;
    if (w >= NN) return;
    int dg = deg[w];
    int o = off[w];
    float ax = 0.f, ay = 0.f;
    int j = 0;
    for (; j + 4 <= dg; j += 4) {
        int s0 = csr[o + j];
        int s1 = csr[o + j + 1];
        int s2 = csr[o + j + 2];
        int s3 = csr[o + j + 3];
        unsigned u0 = xq[(size_t)s0 * 64 + lane];
        unsigned u1 = xq[(size_t)s1 * 64 + lane];
        unsigned u2 = xq[(size_t)s2 * 64 + lane];
        unsigned u3 = xq[(size_t)s3 * 64 + lane];
        f32x2 f0 = fp8x2_to_f32(u0);
        f32x2 f1 = fp8x2_to_f32(u1);
        f32x2 f2 = fp8x2_to_f32(u2);
        f32x2 f3 = fp8x2_to_f32(u3);
        ax += (f0[0] + f1[0]) + (f2[0] + f3[0]);
        ay += (f0[1] + f1[1]) + (f2[1] + f3[1]);
    }
    for (; j < dg; ++j) {
        int s = csr[o + j];
        f32x2 f = fp8x2_to_f32(xq[(size_t)s * 64 + lane]);
        ax += f[0];
        ay += f[1];
    }
    float inv = 1.0f / fmaxf((float)dg, 1.0f);
    unsigned lo = bf16rne(ax * inv);   // feature 2*lane
    unsigned hi = bf16rne(ay * inv);   // feature 2*lane+1
    aggb[(size_t)w * 64 + lane] = (hi << 16) | lo;
}

// MFMA GEMM: x_raw = [agg | x]_bf16 @ Wt^T + b, BN stats fused into epilogue.
// Block: 4 waves; wave: 32 rows x 128 cols = 2x8 tiles of 16x16, K=256 in 8 steps.
__global__ __launch_bounds__(256) void k_gemm(const unsigned short* __restrict__ aggb,
                                              const unsigned short* __restrict__ xb,
                                              const unsigned short* __restrict__ Wt,
                                              const float* __restrict__ bl,
                                              float* __restrict__ out_raw,
                                              float* __restrict__ bn_sum,
                                              float* __restrict__ bn_sq) {
    __shared__ float s_s[4][128];
    __shared__ float s_q[4][128];
    int tid = threadIdx.x;
    int wv = tid >> 6, lane = tid & 63;
    int l15 = lane & 15, lhi = lane >> 4;
    int mr = blockIdx.x * 128 + wv * 32;

    int r0 = mr + l15;       if (r0 > NN - 1) r0 = NN - 1;
    int r1 = mr + 16 + l15;  if (r1 > NN - 1) r1 = NN - 1;
    const unsigned short* a0p = aggb + (size_t)r0 * DD;
    const unsigned short* a1p = aggb + (size_t)r1 * DD;
    const unsigned short* x0p = xb + (size_t)r0 * DD;
    const unsigned short* x1p = xb + (size_t)r1 * DD;

    f32x4 acc[2][8];
    #pragma unroll
    for (int m = 0; m < 2; ++m)
        #pragma unroll
        for (int nt = 0; nt < 8; ++nt)
            acc[m][nt] = (f32x4){0.f, 0.f, 0.f, 0.f};

    #pragma unroll
    for (int ks = 0; ks < 8; ++ks) {
        int kk = (ks & 3) * 32 + lhi * 8;
        bf16x8 a0, a1;
        if (ks < 4) {
            a0 = *(const bf16x8*)(a0p + kk);
            a1 = *(const bf16x8*)(a1p + kk);
        } else {
            a0 = *(const bf16x8*)(x0p + kk);
            a1 = *(const bf16x8*)(x1p + kk);
        }
        #pragma unroll
        for (int nt = 0; nt < 8; ++nt) {
            bf16x8 b = *(const bf16x8*)(Wt + (size_t)(nt * 16 + l15) * 256 + ks * 32 + lhi * 8);
            acc[0][nt] = __builtin_amdgcn_mfma_f32_16x16x32_bf16(a0, b, acc[0][nt], 0, 0, 0);
            acc[1][nt] = __builtin_amdgcn_mfma_f32_16x16x32_bf16(a1, b, acc[1][nt], 0, 0, 0);
        }
    }

    // epilogue: bias + store (D layout: row=lhi*4+reg, col=l15) + column stats
    float bias8[8];
    #pragma unroll
    for (int nt = 0; nt < 8; ++nt) bias8[nt] = bl[nt * 16 + l15];

    float s8[8] = {}, q8[8] = {};
    #pragma unroll
    for (int m = 0; m < 2; ++m) {
        #pragma unroll
        for (int r = 0; r < 4; ++r) {
            int row = mr + m * 16 + lhi * 4 + r;
            if (row < NN) {
                #pragma unroll
                for (int nt = 0; nt < 8; ++nt) {
                    float v = acc[m][nt][r] + bias8[nt];
                    out_raw[(size_t)row * DD + nt * 16 + l15] = v;
                    s8[nt] += v;
                    q8[nt] += v * v;
                }
            }
        }
    }

    // reduce across the 4 lane-groups sharing a column (lane^16, lane^32)
    #pragma unroll
    for (int nt = 0; nt < 8; ++nt) {
        s8[nt] += __shfl_xor(s8[nt], 16);
        s8[nt] += __shfl_xor(s8[nt], 32);
        q8[nt] += __shfl_xor(q8[nt], 16);
        q8[nt] += __shfl_xor(q8[nt], 32);
    }
    if (lhi == 0) {
        #pragma unroll
        for (int nt = 0; nt < 8; ++nt) {
            s_s[wv][nt * 16 + l15] = s8[nt];
            s_q[wv][nt * 16 + l15] = q8[nt];
        }
    }
    __syncthreads();
    if (tid < 128) {
        float ts = s_s[0][tid] + s_s[1][tid] + s_s[2][tid] + s_s[3][tid];
        float tq = s_q[0][tid] + s_q[1][tid] + s_q[2][tid] + s_q[3][tid];
        atomicAdd(&bn_sum[tid], ts);
        atomicAdd(&bn_sq[tid], tq);
    }
}

__global__ __launch_bounds__(256) void k_norm(const float* __restrict__ raw,
                                              const float* __restrict__ bn_sum,
                                              const float* __restrict__ bn_sq,
                                              const float* __restrict__ gamma,
                                              const float* __restrict__ beta,
                                              float* __restrict__ out) {
    const float invN = 1.0f / (float)NN;
    int total = NN * DD / 4;
    for (int idx = blockIdx.x * 256 + threadIdx.x; idx < total; idx += gridDim.x * 256) {
        int cp = idx & 31;
        float4 v = ((const float4*)raw)[idx];
        float4 s = ((const float4*)bn_sum)[cp];
        float4 q = ((const float4*)bn_sq)[cp];
        float4 g = ((const float4*)gamma)[cp];
        float4 b = ((const float4*)beta)[cp];
        float4 o;
        { float mu = s.x * invN; float var = q.x * invN - mu * mu;
          o.x = (v.x - mu) * rsqrtf(var + BN_EPS) * g.x + b.x; }
        { float mu = s.y * invN; float var = q.y * invN - mu * mu;
          o.y = (v.y - mu) * rsqrtf(var + BN_EPS) * g.y + b.y; }
        { float mu = s.z * invN; float var = q.z * invN - mu * mu;
          o.z = (v.z - mu) * rsqrtf(var + BN_EPS) * g.z + b.z; }
        { float mu = s.w * invN; float var = q.w * invN - mu * mu;
          o.w = (v.w - mu) * rsqrtf(var + BN_EPS) * g.w + b.w; }
        ((float4*)out)[idx] = o;
    }
}

extern "C" void kernel_launch(void* const* d_in, const int* in_sizes, int n_in,
                              void* d_out, int out_size, void* d_ws, size_t ws_size,
                              hipStream_t stream) {
    const float* x     = (const float*)d_in[0];
    const int*   ei    = (const int*)d_in[1];
    const float* Wl    = (const float*)d_in[2];
    const float* bl    = (const float*)d_in[3];
    const float* Wr    = (const float*)d_in[4];
    const float* gamma = (const float*)d_in[5];
    const float* beta  = (const float*)d_in[6];

    float* out_raw = (float*)d_out;                       // [NN][DD] x_raw
    float* out_bn  = out_raw + (size_t)NN * DD;           // [NN][DD] x_deskewed
    unsigned* xq   = (unsigned*)d_out;                    // fp8[NN*128] in out_raw half
    unsigned* bin  = (unsigned*)out_bn;                   // uint[NE]
    unsigned* aggb = (unsigned*)out_bn;                   // bf16[NN*128] packed
    unsigned* xb   = (unsigned*)((char*)out_bn + (size_t)NN * DD * 2); // bf16[NN*128]

    char* ws = (char*)d_ws;
    int*   cnt    = (int*)(ws + WS_CNT);
    int*   coff   = (int*)(ws + WS_COFF);
    int*   cur    = (int*)(ws + WS_CUR);
    int*   flag   = (int*)(ws + WS_FLAG);
    float* bn_sum = (float*)(ws + WS_BNSUM);
    float* bn_sq  = (float*)(ws + WS_BNSQ);
    int*   deg    = (int*)(ws + WS_DEG);
    int*   off    = (int*)(ws + WS_OFF);
    int*   csr    = (int*)(ws + WS_CSR);
    unsigned short* Wt = (unsigned short*)(ws + WS_WT);

    hipMemsetAsync(d_ws, 0, WS_ZERO, stream);

    k_detect<<<1, 64, 0, stream>>>(ei, flag);
    k_prep<<<2048, 256, 0, stream>>>(x, xb, xq);
    k_prepw<<<128, 256, 0, stream>>>(Wl, Wr, Wt);
    k_bcount<<<512, 256, 0, stream>>>(ei, flag, cnt);
    k_scan<<<1, 256, 0, stream>>>(cnt, coff, cur);
    k_bin<<<(NE + RND - 1) / RND, 256, 0, stream>>>(ei, flag, cur, bin);
    k_csr<<<NB, 256, 0, stream>>>(bin, coff, csr, deg, off);
    k_agg<<<(NN * 64 + 255) / 256, 256, 0, stream>>>((const unsigned short*)xq, csr, deg, off, aggb);
    k_gemm<<<NB, 256, 0, stream>>>((const unsigned short*)aggb, (const unsigned short*)xb,
                                   Wt, bl, out_raw, bn_sum, bn_sq);
    k_norm<<<4096, 256, 0, stream>>>(out_raw, bn_sum, bn_sq, gamma, beta, out_bn);
}

// Round 10
// 273.070 us; speedup vs baseline: 1.4809x; 1.0988x over previous
//
#include <hip/hip_runtime.h>

constexpr int NN = 100000;
constexpr int NE = 3200000;
constexpr int DD = 128;
constexpr int NB = 782;          // ceil(NN/128) buckets of 128 nodes
constexpr int RND = 8192;        // edges binned per block (391 blocks)
#define BN_EPS 1e-5f

typedef __attribute__((ext_vector_type(8))) short bf16x8;
typedef __attribute__((ext_vector_type(4))) float f32x4;
typedef __attribute__((ext_vector_type(2))) float f32x2;

// ---- workspace layout (bytes) ----
constexpr size_t WS_CNT   = 0;            // int[NB]
constexpr size_t WS_COFF  = 4096;         // int[NB+1]
constexpr size_t WS_CUR   = 8192;         // int[NB]
constexpr size_t WS_FLAG  = 12288;        // int[1]
constexpr size_t WS_BNSUM = 12800;        // float[128]
constexpr size_t WS_BNSQ  = 13312;        // float[128]
constexpr size_t WS_ZERO  = 16384;        // memset range
constexpr size_t WS_DEG   = 16384;        // int[NN]
constexpr size_t WS_OFF   = 416384;       // int[NN]
constexpr size_t WS_CSR   = 816384;       // int[NE]
constexpr size_t WS_WT    = 13616384;     // ushort[128*256] transposed bf16 W (64KB)
// d_out first half (out_raw): xq (fp8[NN*128], 12.8MB) at offset 0, dead after
//   k_agg; k_gemm overwrites with x_raw.
// d_out second half (out_bn): bin (uint[NE]) at [0,12.8M) until k_csr;
//   aggb (bf16[NN*128]) at [0,25.6M) from k_agg; xb (bf16[NN*128]) at [25.6M,51.2M).
//   All dead before k_norm writes x_deskewed.

__device__ inline unsigned bf16rne(float f) {
    unsigned u = __float_as_uint(f);
    return (u + 0x7fffu + ((u >> 16) & 1u)) >> 16;
}

#if __has_builtin(__builtin_amdgcn_cvt_pk_f32_fp8)
__device__ inline f32x2 fp8pk_lo(unsigned u) {
    return __builtin_amdgcn_cvt_pk_f32_fp8((int)u, false);
}
__device__ inline f32x2 fp8pk_hi(unsigned u) {
    return __builtin_amdgcn_cvt_pk_f32_fp8((int)u, true);
}
__device__ inline unsigned f32x4_to_fp8(float4 v) {
    int w = __builtin_amdgcn_cvt_pk_fp8_f32(v.x, v.y, 0, false);
    w = __builtin_amdgcn_cvt_pk_fp8_f32(v.z, v.w, w, true);
    return (unsigned)w;
}
#else
__device__ inline float fp8_to_f32_1(unsigned b) {
    unsigned s = (b & 0x80u) << 24;
    unsigned em = b & 0x7fu;
    float f;
    if (em >= 8) f = __uint_as_float((em << 20) + (120u << 23));
    else f = (float)em * 0.001953125f;
    return __uint_as_float(__float_as_uint(f) | s);
}
__device__ inline f32x2 fp8pk_lo(unsigned u) {
    f32x2 r;
    r[0] = fp8_to_f32_1(u & 0xffu);
    r[1] = fp8_to_f32_1((u >> 8) & 0xffu);
    return r;
}
__device__ inline f32x2 fp8pk_hi(unsigned u) {
    f32x2 r;
    r[0] = fp8_to_f32_1((u >> 16) & 0xffu);
    r[1] = fp8_to_f32_1((u >> 24) & 0xffu);
    return r;
}
__device__ inline unsigned f32_to_fp8_1(float f) {
    unsigned s = (__float_as_uint(f) >> 24) & 0x80u;
    float a = fabsf(f);
    if (!(a > 0.f)) return s;
    if (a >= 448.f) return s | 0x7Eu;
    int e = (int)(__float_as_uint(a) >> 23) - 127;
    if (e < -6) e = -6;
    float step = __uint_as_float((unsigned)(e - 3 + 127) << 23);
    int m = (int)rintf(a / step);
    if (m >= 16) { e += 1; m = 8; }
    if (m >= 8) return s | (unsigned)((e + 7) << 3) | (unsigned)(m - 8);
    return s | (unsigned)m;
}
__device__ inline unsigned f32x4_to_fp8(float4 v) {
    return f32_to_fp8_1(v.x) | (f32_to_fp8_1(v.y) << 8) |
           (f32_to_fp8_1(v.z) << 16) | (f32_to_fp8_1(v.w) << 24);
}
#endif

// Detect whether edge_index arrived as int64 (odd int32 words all zero).
__global__ void k_detect(const int* __restrict__ ei, int* __restrict__ flag) {
    int lane = threadIdx.x;
    int v = ei[2 * lane + 1];
    unsigned long long b = __ballot(v == 0);
    if (lane == 0) *flag = (b == ~0ull) ? 1 : 0;
}

// Build bf16 copy (for GEMM) and fp8 copy (for gather) of x in one pass.
__global__ __launch_bounds__(256) void k_prep(const float* __restrict__ x,
                                              unsigned* __restrict__ xb,
                                              unsigned* __restrict__ xq) {
    int total = NN * DD / 4;
    for (int i = blockIdx.x * 256 + threadIdx.x; i < total; i += gridDim.x * 256) {
        float4 v = ((const float4*)x)[i];
        unsigned a = (bf16rne(v.y) << 16) | bf16rne(v.x);
        unsigned b = (bf16rne(v.w) << 16) | bf16rne(v.z);
        ((uint2*)xb)[i] = make_uint2(a, b);
        xq[i] = f32x4_to_fp8(v);
    }
}

// Transposed bf16 weights: Wt[n][k] (k<128 -> Wl[k][n], else Wr[k-128][n]).
__global__ __launch_bounds__(256) void k_prepw(const float* __restrict__ Wl,
                                               const float* __restrict__ Wr,
                                               unsigned short* __restrict__ Wt) {
    int idx = blockIdx.x * 256 + threadIdx.x;   // 32768 total
    int n = idx >> 8, k = idx & 255;
    float v = (k < 128) ? Wl[(size_t)k * DD + n] : Wr[(size_t)(k - 128) * DD + n];
    Wt[idx] = (unsigned short)bf16rne(v);
}

// Coarse bucket histogram (782 buckets) via block-LDS hist + one flush.
__global__ __launch_bounds__(256) void k_bcount(const int* __restrict__ ei,
                                                const int* __restrict__ flag,
                                                int* __restrict__ cnt) {
    __shared__ int hist[NB];
    for (int i = threadIdx.x; i < NB; i += 256) hist[i] = 0;
    __syncthreads();
    int i64 = *flag;
    int stride = gridDim.x * 256;
    for (int e = blockIdx.x * 256 + threadIdx.x; e < NE; e += stride) {
        int dst = i64 ? ei[2 * (NE + e)] : ei[NE + e];
        atomicAdd(&hist[dst >> 7], 1);
    }
    __syncthreads();
    for (int i = threadIdx.x; i < NB; i += 256) {
        int c = hist[i];
        if (c) atomicAdd(&cnt[i], c);
    }
}

// Exclusive scan of the 782 bucket counts.
__global__ __launch_bounds__(256) void k_scan(const int* __restrict__ cnt,
                                              int* __restrict__ coff,
                                              int* __restrict__ cur) {
    __shared__ int s[NB];
    for (int i = threadIdx.x; i < NB; i += 256) s[i] = cnt[i];
    __syncthreads();
    if (threadIdx.x == 0) {
        int acc = 0;
        for (int i = 0; i < NB; ++i) { int c = s[i]; s[i] = acc; acc += c; }
    }
    __syncthreads();
    for (int i = threadIdx.x; i < NB; i += 256) { coff[i] = s[i]; cur[i] = s[i]; }
    if (threadIdx.x == 0) coff[NB] = NE;
}

// Bin edges by coarse bucket with per-block batched cursor reservation.
__global__ __launch_bounds__(256) void k_bin(const int* __restrict__ ei,
                                             const int* __restrict__ flag,
                                             int* __restrict__ cur,
                                             unsigned* __restrict__ bin) {
    __shared__ int hist[NB];
    __shared__ int base[NB];
    __shared__ int rk[NB];
    int tid = threadIdx.x;
    for (int i = tid; i < NB; i += 256) { hist[i] = 0; rk[i] = 0; }
    __syncthreads();
    int i64 = *flag;
    int e0 = blockIdx.x * RND;
    for (int j = tid; j < RND; j += 256) {
        int e = e0 + j;
        if (e < NE) {
            int dst = i64 ? ei[2 * (NE + e)] : ei[NE + e];
            atomicAdd(&hist[dst >> 7], 1);
        }
    }
    __syncthreads();
    for (int b = tid; b < NB; b += 256) {
        int c = hist[b];
        if (c > 0) base[b] = atomicAdd(&cur[b], c);
    }
    __syncthreads();
    for (int j = tid; j < RND; j += 256) {
        int e = e0 + j;
        if (e < NE) {
            int src = i64 ? ei[2 * e] : ei[e];
            int dst = i64 ? ei[2 * (NE + e)] : ei[NE + e];
            int b = dst >> 7;
            int r = atomicAdd(&rk[b], 1);
            bin[base[b] + r] = ((unsigned)src << 7) | (unsigned)(dst & 127);
        }
    }
}

// Per-bucket counting sort -> node-grouped CSR + deg/off.
__global__ __launch_bounds__(256) void k_csr(const unsigned* __restrict__ bin,
                                             const int* __restrict__ coff,
                                             int* __restrict__ csr,
                                             int* __restrict__ deg,
                                             int* __restrict__ off) {
    __shared__ int hist[128];
    __shared__ int sb[128];
    __shared__ int curs[128];
    int b = blockIdx.x;
    int tid = threadIdx.x;
    if (tid < 128) hist[tid] = 0;
    __syncthreads();
    int e0 = coff[b], e1 = coff[b + 1];
    for (int j = e0 + tid; j < e1; j += 256)
        atomicAdd(&hist[bin[j] & 127], 1);
    __syncthreads();
    if (tid == 0) {
        int acc = 0;
        for (int i = 0; i < 128; ++i) { sb[i] = acc; acc += hist[i]; }
    }
    __syncthreads();
    if (tid < 128) curs[tid] = sb[tid];
    __syncthreads();
    for (int j = e0 + tid; j < e1; j += 256) {
        unsigned p = bin[j];
        int d = p & 127;
        int r = atomicAdd(&curs[d], 1);
        csr[e0 + r] = (int)(p >> 7);
    }
    int n = b * 128 + tid;
    if (tid < 128 && n < NN) {
        deg[n] = hist[tid];
        off[n] = e0 + sb[tid];
    }
}

// Wave-per-node gather-sum from the fp8 copy, 2 rows per wave-load:
// each lane loads a uint (4 fp8); lanes 0-31 = even edge, 32-63 = odd edge.
// Unroll 4 -> 8 edges in flight. Cross-half combine via 4x shfl_xor(32).
__global__ __launch_bounds__(256) void k_agg(const unsigned* __restrict__ xq,
                                             const int* __restrict__ csr,
                                             const int* __restrict__ deg,
                                             const int* __restrict__ off,
                                             unsigned* __restrict__ aggb) {
    int w = (blockIdx.x * 256 + threadIdx.x) >> 6;
    int lane = threadIdx.x & 63;
    if (w >= NN) return;
    int dg = deg[w];
    int o = off[w];
    int half = lane >> 5;     // which of the 2 edges this lane loads
    int cl = lane & 31;       // uint slot within the 128B row
    float a0 = 0.f, a1 = 0.f, a2 = 0.f, a3 = 0.f;

    int j = 0;
    for (; j + 8 <= dg; j += 8) {
        int s0 = csr[o + j + 0 + half];
        int s1 = csr[o + j + 2 + half];
        int s2 = csr[o + j + 4 + half];
        int s3 = csr[o + j + 6 + half];
        unsigned u0 = xq[(size_t)s0 * 32 + cl];
        unsigned u1 = xq[(size_t)s1 * 32 + cl];
        unsigned u2 = xq[(size_t)s2 * 32 + cl];
        unsigned u3 = xq[(size_t)s3 * 32 + cl];
        f32x2 l0 = fp8pk_lo(u0), h0 = fp8pk_hi(u0);
        f32x2 l1 = fp8pk_lo(u1), h1 = fp8pk_hi(u1);
        f32x2 l2 = fp8pk_lo(u2), h2 = fp8pk_hi(u2);
        f32x2 l3 = fp8pk_lo(u3), h3 = fp8pk_hi(u3);
        a0 += (l0[0] + l1[0]) + (l2[0] + l3[0]);
        a1 += (l0[1] + l1[1]) + (l2[1] + l3[1]);
        a2 += (h0[0] + h1[0]) + (h2[0] + h3[0]);
        a3 += (h0[1] + h1[1]) + (h2[1] + h3[1]);
    }
    for (; j + 2 <= dg; j += 2) {
        int s = csr[o + j + half];
        unsigned u = xq[(size_t)s * 32 + cl];
        f32x2 l = fp8pk_lo(u), h = fp8pk_hi(u);
        a0 += l[0]; a1 += l[1]; a2 += h[0]; a3 += h[1];
    }
    if (j < dg && half == 0) {   // last odd edge: half 0 only
        int s = csr[o + j];
        unsigned u = xq[(size_t)s * 32 + cl];
        f32x2 l = fp8pk_lo(u), h = fp8pk_hi(u);
        a0 += l[0]; a1 += l[1]; a2 += h[0]; a3 += h[1];
    }

    a0 += __shfl_xor(a0, 32);
    a1 += __shfl_xor(a1, 32);
    a2 += __shfl_xor(a2, 32);
    a3 += __shfl_xor(a3, 32);

    if (half == 0) {
        float inv = 1.0f / fmaxf((float)dg, 1.0f);
        unsigned p0 = (bf16rne(a1 * inv) << 16) | bf16rne(a0 * inv);  // feats 4cl,4cl+1
        unsigned p1 = (bf16rne(a3 * inv) << 16) | bf16rne(a2 * inv);  // feats 4cl+2,4cl+3
        ((uint2*)aggb)[(size_t)w * 32 + cl] = make_uint2(p0, p1);
    }
}

// MFMA GEMM: x_raw = [agg | x]_bf16 @ Wt^T + b, BN stats fused into epilogue.
// Block: 4 waves; wave: 32 rows x 128 cols = 2x8 tiles of 16x16, K=256 in 8 steps.
__global__ __launch_bounds__(256) void k_gemm(const unsigned short* __restrict__ aggb,
                                              const unsigned short* __restrict__ xb,
                                              const unsigned short* __restrict__ Wt,
                                              const float* __restrict__ bl,
                                              float* __restrict__ out_raw,
                                              float* __restrict__ bn_sum,
                                              float* __restrict__ bn_sq) {
    __shared__ float s_s[4][128];
    __shared__ float s_q[4][128];
    int tid = threadIdx.x;
    int wv = tid >> 6, lane = tid & 63;
    int l15 = lane & 15, lhi = lane >> 4;
    int mr = blockIdx.x * 128 + wv * 32;

    int r0 = mr + l15;       if (r0 > NN - 1) r0 = NN - 1;
    int r1 = mr + 16 + l15;  if (r1 > NN - 1) r1 = NN - 1;
    const unsigned short* a0p = aggb + (size_t)r0 * DD;
    const unsigned short* a1p = aggb + (size_t)r1 * DD;
    const unsigned short* x0p = xb + (size_t)r0 * DD;
    const unsigned short* x1p = xb + (size_t)r1 * DD;

    f32x4 acc[2][8];
    #pragma unroll
    for (int m = 0; m < 2; ++m)
        #pragma unroll
        for (int nt = 0; nt < 8; ++nt)
            acc[m][nt] = (f32x4){0.f, 0.f, 0.f, 0.f};

    #pragma unroll
    for (int ks = 0; ks < 8; ++ks) {
        int kk = (ks & 3) * 32 + lhi * 8;
        bf16x8 a0, a1;
        if (ks < 4) {
            a0 = *(const bf16x8*)(a0p + kk);
            a1 = *(const bf16x8*)(a1p + kk);
        } else {
            a0 = *(const bf16x8*)(x0p + kk);
            a1 = *(const bf16x8*)(x1p + kk);
        }
        #pragma unroll
        for (int nt = 0; nt < 8; ++nt) {
            bf16x8 b = *(const bf16x8*)(Wt + (size_t)(nt * 16 + l15) * 256 + ks * 32 + lhi * 8);
            acc[0][nt] = __builtin_amdgcn_mfma_f32_16x16x32_bf16(a0, b, acc[0][nt], 0, 0, 0);
            acc[1][nt] = __builtin_amdgcn_mfma_f32_16x16x32_bf16(a1, b, acc[1][nt], 0, 0, 0);
        }
    }

    // epilogue: bias + store (D layout: row=lhi*4+reg, col=l15) + column stats
    float bias8[8];
    #pragma unroll
    for (int nt = 0; nt < 8; ++nt) bias8[nt] = bl[nt * 16 + l15];

    float s8[8] = {}, q8[8] = {};
    #pragma unroll
    for (int m = 0; m < 2; ++m) {
        #pragma unroll
        for (int r = 0; r < 4; ++r) {
            int row = mr + m * 16 + lhi * 4 + r;
            if (row < NN) {
                #pragma unroll
                for (int nt = 0; nt < 8; ++nt) {
                    float v = acc[m][nt][r] + bias8[nt];
                    out_raw[(size_t)row * DD + nt * 16 + l15] = v;
                    s8[nt] += v;
                    q8[nt] += v * v;
                }
            }
        }
    }

    // reduce across the 4 lane-groups sharing a column (lane^16, lane^32)
    #pragma unroll
    for (int nt = 0; nt < 8; ++nt) {
        s8[nt] += __shfl_xor(s8[nt], 16);
        s8[nt] += __shfl_xor(s8[nt], 32);
        q8[nt] += __shfl_xor(q8[nt], 16);
        q8[nt] += __shfl_xor(q8[nt], 32);
    }
    if (lhi == 0) {
        #pragma unroll
        for (int nt = 0; nt < 8; ++nt) {
            s_s[wv][nt * 16 + l15] = s8[nt];
            s_q[wv][nt * 16 + l15] = q8[nt];
        }
    }
    __syncthreads();
    if (tid < 128) {
        float ts = s_s[0][tid] + s_s[1][tid] + s_s[2][tid] + s_s[3][tid];
        float tq = s_q[0][tid] + s_q[1][tid] + s_q[2][tid] + s_q[3][tid];
        atomicAdd(&bn_sum[tid], ts);
        atomicAdd(&bn_sq[tid], tq);
    }
}

__global__ __launch_bounds__(256) void k_norm(const float* __restrict__ raw,
                                              const float* __restrict__ bn_sum,
                                              const float* __restrict__ bn_sq,
                                              const float* __restrict__ gamma,
                                              const float* __restrict__ beta,
                                              float* __restrict__ out) {
    const float invN = 1.0f / (float)NN;
    int total = NN * DD / 4;
    for (int idx = blockIdx.x * 256 + threadIdx.x; idx < total; idx += gridDim.x * 256) {
        int cp = idx & 31;
        float4 v = ((const float4*)raw)[idx];
        float4 s = ((const float4*)bn_sum)[cp];
        float4 q = ((const float4*)bn_sq)[cp];
        float4 g = ((const float4*)gamma)[cp];
        float4 b = ((const float4*)beta)[cp];
        float4 o;
        { float mu = s.x * invN; float var = q.x * invN - mu * mu;
          o.x = (v.x - mu) * rsqrtf(var + BN_EPS) * g.x + b.x; }
        { float mu = s.y * invN; float var = q.y * invN - mu * mu;
          o.y = (v.y - mu) * rsqrtf(var + BN_EPS) * g.y + b.y; }
        { float mu = s.z * invN; float var = q.z * invN - mu * mu;
          o.z = (v.z - mu) * rsqrtf(var + BN_EPS) * g.z + b.z; }
        { float mu = s.w * invN; float var = q.w * invN - mu * mu;
          o.w = (v.w - mu) * rsqrtf(var + BN_EPS) * g.w + b.w; }
        ((float4*)out)[idx] = o;
    }
}

extern "C" void kernel_launch(void* const* d_in, const int* in_sizes, int n_in,
                              void* d_out, int out_size, void* d_ws, size_t ws_size,
                              hipStream_t stream) {
    const float* x     = (const float*)d_in[0];
    const int*   ei    = (const int*)d_in[1];
    const float* Wl    = (const float*)d_in[2];
    const float* bl    = (const float*)d_in[3];
    const float* Wr    = (const float*)d_in[4];
    const float* gamma = (const float*)d_in[5];
    const float* beta  = (const float*)d_in[6];

    float* out_raw = (float*)d_out;                       // [NN][DD] x_raw
    float* out_bn  = out_raw + (size_t)NN * DD;           // [NN][DD] x_deskewed
    unsigned* xq   = (unsigned*)d_out;                    // fp8[NN*128] in out_raw half
    unsigned* bin  = (unsigned*)out_bn;                   // uint[NE]
    unsigned* aggb = (unsigned*)out_bn;                   // bf16[NN*128] packed
    unsigned* xb   = (unsigned*)((char*)out_bn + (size_t)NN * DD * 2); // bf16[NN*128]

    char* ws = (char*)d_ws;
    int*   cnt    = (int*)(ws + WS_CNT);
    int*   coff   = (int*)(ws + WS_COFF);
    int*   cur    = (int*)(ws + WS_CUR);
    int*   flag   = (int*)(ws + WS_FLAG);
    float* bn_sum = (float*)(ws + WS_BNSUM);
    float* bn_sq  = (float*)(ws + WS_BNSQ);
    int*   deg    = (int*)(ws + WS_DEG);
    int*   off    = (int*)(ws + WS_OFF);
    int*   csr    = (int*)(ws + WS_CSR);
    unsigned short* Wt = (unsigned short*)(ws + WS_WT);

    hipMemsetAsync(d_ws, 0, WS_ZERO, stream);

    k_detect<<<1, 64, 0, stream>>>(ei, flag);
    k_prep<<<2048, 256, 0, stream>>>(x, xb, xq);
    k_prepw<<<128, 256, 0, stream>>>(Wl, Wr, Wt);
    k_bcount<<<512, 256, 0, stream>>>(ei, flag, cnt);
    k_scan<<<1, 256, 0, stream>>>(cnt, coff, cur);
    k_bin<<<(NE + RND - 1) / RND, 256, 0, stream>>>(ei, flag, cur, bin);
    k_csr<<<NB, 256, 0, stream>>>(bin, coff, csr, deg, off);
    k_agg<<<(NN * 64 + 255) / 256, 256, 0, stream>>>(xq, csr, deg, off, aggb);
    k_gemm<<<NB, 256, 0, stream>>>((const unsigned short*)aggb, (const unsigned short*)xb,
                                   Wt, bl, out_raw, bn_sum, bn_sq);
    k_norm<<<4096, 256, 0, stream>>>(out_raw, bn_sum, bn_sq, gamma, beta, out_bn);
}